// Round 9
// baseline (72.296 us; speedup 1.0000x reference)
//
#include <hip/hip_runtime.h>
#include <math.h>

#define DDIM 256       // D
#define NSLOT 4096     // N (power of 2)
#define LOG2_NSLOT 12
#define ROWS_PER_BLOCK 32   // 4 waves x 8 groups x 1 row  (proven layout)

typedef float f32x4 __attribute__((ext_vector_type(4)));

// ---------------------------------------------------------------------------
// Kernel 1: e[b,n] = exp(beta[b] * cosine(m[b,n,:], k[b,:]))  (no max-sub:
// beta in [0,1), cos in [-1,1] => score in (-1,1), exp in (0.37, 2.72) --
// softmax max-subtraction is numerically unnecessary). Also accumulates the
// per-batch softmax denominator: after the intra-group butterfly the 8 lanes
// of a group hold identical e; the cross-group butterfly (xor 8,16,32) runs
// 8 independent parallel butterflies, each summing the 8 DISTINCT group
// values exactly once (NO /8 -- round-8 bug). One relaxed agent-scope fp64
// atomicAdd per block (128/batch; relaxed => no L2 flush, cf. round-5 bug).
// ---------------------------------------------------------------------------
__global__ __launch_bounds__(256) void ntm_score_kernel(
    const float* __restrict__ m, const float* __restrict__ k,
    const float* __restrict__ beta, float* __restrict__ escores,
    double* __restrict__ bsums) {
  const int tid  = threadIdx.x;
  const int wave = tid >> 6;
  const int lane = tid & 63;
  const int grp  = lane >> 3;   // row within wave (0..7)
  const int l    = lane & 7;    // lane within row group
  const long long row =
      (long long)blockIdx.x * ROWS_PER_BLOCK + wave * 8 + grp;
  const int b = (int)(row >> LOG2_NSLOT);

  const float* mrow = m + row * DDIM;
  const float* krow = k + (long long)b * DDIM;

  float dot = 0.f, mm = 0.f, kk = 0.f;
  #pragma unroll
  for (int j = 0; j < 8; ++j) {
    const int off = j * 32 + l * 4;
    const f32x4 mv = *reinterpret_cast<const f32x4*>(mrow + off);
    const f32x4 kv = *reinterpret_cast<const f32x4*>(krow + off);
    dot += mv.x * kv.x + mv.y * kv.y + mv.z * kv.z + mv.w * kv.w;
    mm  += mv.x * mv.x + mv.y * mv.y + mv.z * mv.z + mv.w * mv.w;
    kk  += kv.x * kv.x + kv.y * kv.y + kv.z * kv.z + kv.w * kv.w;
  }

  #pragma unroll
  for (int off = 4; off > 0; off >>= 1) {
    dot += __shfl_xor(dot, off);
    mm  += __shfl_xor(mm, off);
    kk  += __shfl_xor(kk, off);
  }

  // all 8 lanes of the group hold the reduced dot/mm/kk (xor = butterfly)
  const float mn = fmaxf(sqrtf(mm), 1e-8f);
  const float kn = fmaxf(sqrtf(kk), 1e-8f);
  const float e  = expf(beta[b] * (dot / (mn * kn)));
  if (l == 0) escores[row] = e;

  // cross-group wave sum: each of the 8 distinct group values counted once
  double de = (double)e;
  de += __shfl_xor(de, 8);
  de += __shfl_xor(de, 16);
  de += __shfl_xor(de, 32);

  __shared__ double wsum[4];
  if (lane == 0) wsum[wave] = de;
  __syncthreads();
  if (tid == 0) {
    const double blocksum = wsum[0] + wsum[1] + wsum[2] + wsum[3];
    __hip_atomic_fetch_add(&bsums[b], blocksum, __ATOMIC_RELAXED,
                           __HIP_MEMORY_SCOPE_AGENT);
  }
}

// ---------------------------------------------------------------------------
// Kernel 2: per batch row (1 block of 1024 threads, 4 elems/thread):
//   w = e/sum + (1-g)*w_prev -> circular 3-tap shift -> w^r -> renorm.
// Max/exp/sum phases moved into kernel 1; this kernel has ONE reduction.
// ---------------------------------------------------------------------------
__global__ __launch_bounds__(1024) void ntm_finish_kernel(
    const float* __restrict__ escores, const double* __restrict__ bsums,
    const float* __restrict__ g, const float* __restrict__ s,
    const float* __restrict__ r, const float* __restrict__ w_prev,
    float* __restrict__ out) {
  const int b = blockIdx.x;
  const int tid = threadIdx.x;
  const int wave = tid >> 6;
  const int lane = tid & 63;

  __shared__ float  w_sh[NSLOT];
  __shared__ double redd[16];
  __shared__ double bcast_d;

  const float* sc = escores + (size_t)b * NSLOT;
  const float* wp = w_prev + (size_t)b * NSLOT;

  const double inv_sum = 1.0 / bsums[b];
  const float gm1 = 1.0f - g[b];

  // ---- normalize + interpolate, stash in LDS for the shift ----
  #pragma unroll
  for (int i = 0; i < 4; ++i) {
    const int n = tid + i * 1024;
    w_sh[n] = (float)((double)sc[n] * inv_sum) + gm1 * wp[n];
  }
  __syncthreads();

  // ---- circular shift: w_new[n] = s0*w[n-1] + s1*w[n] + s2*w[n+1] ----
  const float s0 = s[b * 3 + 0];
  const float s1 = s[b * 3 + 1];
  const float s2 = s[b * 3 + 2];
  const float rv = r[b];

  float p[4];
  double psum = 0.0;
  #pragma unroll
  for (int i = 0; i < 4; ++i) {
    const int n = tid + i * 1024;
    const float left  = w_sh[(n + NSLOT - 1) & (NSLOT - 1)];
    const float mid   = w_sh[n];
    const float right = w_sh[(n + 1) & (NSLOT - 1)];
    const float v = s0 * left + s1 * mid + s2 * right;
    p[i] = powf(v, rv);
    psum += (double)p[i];
  }
  #pragma unroll
  for (int off = 32; off > 0; off >>= 1) psum += __shfl_xor(psum, off);
  if (lane == 0) redd[wave] = psum;
  __syncthreads();
  if (tid == 0) {
    double v = 1e-16;
    #pragma unroll
    for (int i = 0; i < 16; ++i) v += redd[i];
    bcast_d = v;
  }
  __syncthreads();
  const double inv_p = 1.0 / bcast_d;

  float* o = out + (size_t)b * NSLOT;
  #pragma unroll
  for (int i = 0; i < 4; ++i) {
    o[tid + i * 1024] = (float)((double)p[i] * inv_p);
  }
}

// ---------------------------------------------------------------------------
extern "C" void kernel_launch(void* const* d_in, const int* in_sizes, int n_in,
                              void* d_out, int out_size, void* d_ws, size_t ws_size,
                              hipStream_t stream) {
  const float* m      = (const float*)d_in[0];  // [B, N, D]
  const float* k      = (const float*)d_in[1];  // [B, D]
  const float* beta   = (const float*)d_in[2];  // [B, 1]
  const float* g      = (const float*)d_in[3];  // [B, 1]
  const float* s      = (const float*)d_in[4];  // [B, 3]
  const float* r      = (const float*)d_in[5];  // [B, 1]
  const float* w_prev = (const float*)d_in[6];  // [B, N]
  float* out = (float*)d_out;                   // [B, N]

  const int B = in_sizes[1] / DDIM;             // k is [B, D]
  const int rows = B * NSLOT;

  float*  escores = (float*)d_ws;                                  // [B*N]
  double* bsums   = (double*)((char*)d_ws + (size_t)rows * sizeof(float));

  // zero the per-batch denominators (graph-capturable memset node)
  hipMemsetAsync(bsums, 0, B * sizeof(double), stream);

  ntm_score_kernel<<<rows / ROWS_PER_BLOCK, 256, 0, stream>>>(
      m, k, beta, escores, bsums);
  ntm_finish_kernel<<<B, 1024, 0, stream>>>(
      escores, bsums, g, s, r, w_prev, out);
}

// Round 10
// 50.353 us; speedup vs baseline: 1.4358x; 1.4358x over previous
//
#include <hip/hip_runtime.h>
#include <math.h>

#define DDIM 256       // D
#define NSLOT 4096     // N (power of 2)
#define LOG2_NSLOT 12
#define ROWS_PER_BLOCK 32   // 4 waves x 8 groups x 1 row  (proven round-6 layout)

typedef float f32x4 __attribute__((ext_vector_type(4)));

// ---------------------------------------------------------------------------
// Kernel 1: e[b,n] = exp(beta[b] * cosine(m[b,n,:], k[b,:])).
// No softmax max-subtraction needed: beta in [0,1), cos in [-1,1] => exp in
// (0.37, 2.72) -- verified absmax 0.0 in rounds 8/9. NO cross-block atomics:
// contended device-scope atomics cost ~21us (round 9) / ~470us (round 5);
// the per-batch sum belongs in kernel 2.
// ---------------------------------------------------------------------------
__global__ __launch_bounds__(256) void ntm_score_kernel(
    const float* __restrict__ m, const float* __restrict__ k,
    const float* __restrict__ beta, float* __restrict__ escores) {
  const int wave = threadIdx.x >> 6;
  const int lane = threadIdx.x & 63;
  const int grp  = lane >> 3;   // row within wave (0..7)
  const int l    = lane & 7;    // lane within row group
  const long long row =
      (long long)blockIdx.x * ROWS_PER_BLOCK + wave * 8 + grp;
  const int b = (int)(row >> LOG2_NSLOT);

  const float* mrow = m + row * DDIM;
  const float* krow = k + (long long)b * DDIM;

  float dot = 0.f, mm = 0.f, kk = 0.f;
  #pragma unroll
  for (int j = 0; j < 8; ++j) {
    const int off = j * 32 + l * 4;
    const f32x4 mv = *reinterpret_cast<const f32x4*>(mrow + off);
    const f32x4 kv = *reinterpret_cast<const f32x4*>(krow + off);
    dot += mv.x * kv.x + mv.y * kv.y + mv.z * kv.z + mv.w * kv.w;
    mm  += mv.x * mv.x + mv.y * mv.y + mv.z * mv.z + mv.w * mv.w;
    kk  += kv.x * kv.x + kv.y * kv.y + kv.z * kv.z + kv.w * kv.w;
  }

  #pragma unroll
  for (int off = 4; off > 0; off >>= 1) {
    dot += __shfl_xor(dot, off);
    mm  += __shfl_xor(mm, off);
    kk  += __shfl_xor(kk, off);
  }

  if (l == 0) {
    const float mn = fmaxf(sqrtf(mm), 1e-8f);
    const float kn = fmaxf(sqrtf(kk), 1e-8f);
    escores[row] = expf(beta[b] * (dot / (mn * kn)));
  }
}

// ---------------------------------------------------------------------------
// Kernel 2: per batch row (1 block of 1024 threads, 4 elems/thread):
//   sum(e) -> w = e/sum + (1-g)*w_prev -> 3-tap circular shift -> w^r ->
//   renorm. Two fp64 reductions (was three: max phase + expf pass removed).
// ---------------------------------------------------------------------------
__global__ __launch_bounds__(1024) void ntm_finish_kernel(
    const float* __restrict__ escores, const float* __restrict__ g,
    const float* __restrict__ s, const float* __restrict__ r,
    const float* __restrict__ w_prev, float* __restrict__ out) {
  const int b = blockIdx.x;
  const int tid = threadIdx.x;
  const int wave = tid >> 6;
  const int lane = tid & 64 - 1;  // & 63

  __shared__ float  w_sh[NSLOT];
  __shared__ double redd[16];
  __shared__ double bcast_d;

  const float* sc = escores + (size_t)b * NSLOT;
  const float* wp = w_prev + (size_t)b * NSLOT;

  // ---- load e, block sum (fp64) ----
  float e[4];
  double dsum = 0.0;
  #pragma unroll
  for (int i = 0; i < 4; ++i) {
    e[i] = sc[tid + i * 1024];
    dsum += (double)e[i];
  }
  #pragma unroll
  for (int off = 32; off > 0; off >>= 1) dsum += __shfl_xor(dsum, off);
  if (lane == 0) redd[wave] = dsum;
  __syncthreads();
  if (tid == 0) {
    double v = 0.0;
    #pragma unroll
    for (int i = 0; i < 16; ++i) v += redd[i];
    bcast_d = v;
  }
  __syncthreads();
  const double inv_sum = 1.0 / bcast_d;

  // ---- normalize + interpolate, stash in LDS for the shift ----
  const float gm1 = 1.0f - g[b];
  #pragma unroll
  for (int i = 0; i < 4; ++i) {
    const int n = tid + i * 1024;
    w_sh[n] = (float)((double)e[i] * inv_sum) + gm1 * wp[n];
  }
  __syncthreads();

  // ---- circular shift: w_new[n] = s0*w[n-1] + s1*w[n] + s2*w[n+1] ----
  const float s0 = s[b * 3 + 0];
  const float s1 = s[b * 3 + 1];
  const float s2 = s[b * 3 + 2];
  const float rv = r[b];

  float p[4];
  double psum = 0.0;
  #pragma unroll
  for (int i = 0; i < 4; ++i) {
    const int n = tid + i * 1024;
    const float left  = w_sh[(n + NSLOT - 1) & (NSLOT - 1)];
    const float mid   = w_sh[n];
    const float right = w_sh[(n + 1) & (NSLOT - 1)];
    const float v = s0 * left + s1 * mid + s2 * right;
    p[i] = powf(v, rv);
    psum += (double)p[i];
  }
  #pragma unroll
  for (int off = 32; off > 0; off >>= 1) psum += __shfl_xor(psum, off);
  if (lane == 0) redd[wave] = psum;
  __syncthreads();
  if (tid == 0) {
    double v = 1e-16;
    #pragma unroll
    for (int i = 0; i < 16; ++i) v += redd[i];
    bcast_d = v;
  }
  __syncthreads();
  const double inv_p = 1.0 / bcast_d;

  float* o = out + (size_t)b * NSLOT;
  #pragma unroll
  for (int i = 0; i < 4; ++i) {
    o[tid + i * 1024] = (float)((double)p[i] * inv_p);
  }
}

// ---------------------------------------------------------------------------
extern "C" void kernel_launch(void* const* d_in, const int* in_sizes, int n_in,
                              void* d_out, int out_size, void* d_ws, size_t ws_size,
                              hipStream_t stream) {
  const float* m      = (const float*)d_in[0];  // [B, N, D]
  const float* k      = (const float*)d_in[1];  // [B, D]
  const float* beta   = (const float*)d_in[2];  // [B, 1]
  const float* g      = (const float*)d_in[3];  // [B, 1]
  const float* s      = (const float*)d_in[4];  // [B, 3]
  const float* r      = (const float*)d_in[5];  // [B, 1]
  const float* w_prev = (const float*)d_in[6];  // [B, N]
  float* out = (float*)d_out;                   // [B, N]
  float* escores = (float*)d_ws;                // [B, N] scratch (1 MB)

  const int B = in_sizes[1] / DDIM;             // k is [B, D]
  const int rows = B * NSLOT;

  ntm_score_kernel<<<rows / ROWS_PER_BLOCK, 256, 0, stream>>>(m, k, beta, escores);
  ntm_finish_kernel<<<B, 1024, 0, stream>>>(escores, g, s, r, w_prev, out);
}